// Round 14
// baseline (170.226 us; speedup 1.0000x reference)
//
#include <hip/hip_runtime.h>

typedef float f4v __attribute__((ext_vector_type(4)));   // MFMA accumulator
typedef int   i8v __attribute__((ext_vector_type(8)));   // 32 fp8 bytes (8 VGPRs)

#define LOG2E 1.4426950408889634f
#define LN2   0.6931471805599453f
#define SC1   0x7F7F7F7F   // four e8m0 scale factors of 1.0

// Raw barrier: LDS visibility only (lgkmcnt); vmcnt floats -> global prefetch stays async.
#define SYNC_LDS() __asm__ __volatile__("s_waitcnt lgkmcnt(0)\n\ts_barrier" ::: "memory")

__device__ __forceinline__ float fast_exp2(float x) {
#if __has_builtin(__builtin_amdgcn_exp2f)
    return __builtin_amdgcn_exp2f(x);
#else
    return exp2f(x);
#endif
}

// f32 -> bf8 (e5m2) low byte. e5m2 range ~2^-16..2^15.5 absorbs stale-renorm drift.
__device__ __forceinline__ unsigned char f2bf8(float x) {
    return (unsigned char)(__builtin_amdgcn_cvt_pk_bf8_f32(x, x, 0, false) & 0xff);
}

// MIDDLE-MEET (R13-proven): 256 blocks. Blocks 0..127: forward chain of batch b
//   v_t = diag(g_t) E^T v_{t-1}, 255 steps (E-COLUMN frags, colmax norm).
// Blocks 128..255: backward chain, w_{t-1} = E (g_t (*) w_t), 256 steps
//   (E-ROW frags, rowmax norm; final step applies rowmax only).
// Z_b = ln(v_255 . w_255) + (C_f + C_b) ln2.
// R14: peeled final step, pointer-swap dbuf, branchless prefetch, fused tail kernel.
__launch_bounds__(256, 1)
__global__ void crf_main(const float* __restrict__ emissions,
                         const float* __restrict__ trans,
                         float* __restrict__ V,  float* __restrict__ W,
                         float* __restrict__ CF, float* __restrict__ CB,
                         int* __restrict__ counter) {
    const int T = 512, N = 256;
    const bool fwd = blockIdx.x < 128;
    const int b  = fwd ? blockIdx.x : blockIdx.x - 128;
    const int j  = threadIdx.x;
    const int l  = j & 63;          // lane
    const int w  = j >> 6;          // wave
    const int lg = l >> 4;          // 16-lane group (K sub-chunk)
    const int ll = l & 15;          // position in group (N dim)

    if (blockIdx.x == 0 && j == 0) *counter = 0;   // reset tail-kernel ticket

    __shared__ alignas(16) unsigned char u_lds[2][256];  // u as bf8, double-buffered
    __shared__ float cm2_lds[256];

    // ---- per-state log2 normalizer: fwd = colmax(trans[:,j]), bwd = rowmax(trans[j,:]) ----
    if (fwd) {
        const float* tcol = trans + j;
        float m = -1e30f;
        #pragma unroll 8
        for (int i = 0; i < N; ++i) m = fmaxf(m, tcol[i * N]);
        cm2_lds[j] = m * LOG2E;
    } else {
        const float4* trow = (const float4*)(trans + (size_t)j * N);
        float m = -1e30f;
        #pragma unroll 8
        for (int i = 0; i < 64; ++i) {
            float4 t4 = trow[i];
            m = fmaxf(m, fmaxf(fmaxf(t4.x, t4.y), fmaxf(t4.z, t4.w)));
        }
        cm2_lds[j] = m * LOG2E;
    }
    __syncthreads();
    const float cm2 = cm2_lds[j];   // own state's normalizer

    // ---- E fragments (B operand) as fp8 e4m3, identity k-map (byte-slot == k) ----
    i8v Efr[4][2];
    #pragma unroll
    for (int c = 0; c < 4; ++c) {
        const int   col = 64 * w + 16 * c + ll;
        const float cc  = cm2_lds[col];
        #pragma unroll
        for (int q = 0; q < 2; ++q) {
            i8v ev;
            #pragma unroll
            for (int d = 0; d < 8; ++d) {
                const int k0 = 128 * q + 32 * lg + 4 * d;
                float f0, f1, f2, f3;
                if (fwd) {
                    f0 = fast_exp2(trans[(size_t)(k0 + 0) * N + col] * LOG2E - cc);
                    f1 = fast_exp2(trans[(size_t)(k0 + 1) * N + col] * LOG2E - cc);
                    f2 = fast_exp2(trans[(size_t)(k0 + 2) * N + col] * LOG2E - cc);
                    f3 = fast_exp2(trans[(size_t)(k0 + 3) * N + col] * LOG2E - cc);
                } else {
                    float4 t4 = *(const float4*)(trans + (size_t)col * N + k0);
                    f0 = fast_exp2(t4.x * LOG2E - cc);
                    f1 = fast_exp2(t4.y * LOG2E - cc);
                    f2 = fast_exp2(t4.z * LOG2E - cc);
                    f3 = fast_exp2(t4.w * LOG2E - cc);
                }
                int pk = __builtin_amdgcn_cvt_pk_fp8_f32(f0, f1, 0, false);
                pk     = __builtin_amdgcn_cvt_pk_fp8_f32(f2, f3, pk, true);
                ev[d] = pk;
            }
            Efr[c][q] = ev;
        }
    }

    // ---- init: u = bf8(2^(log2e * emit[first])), C = 0; depth-2 em prefetch ----
    const float* em_j = emissions + ((size_t)b * T) * N + j;
    u_lds[0][j] = f2bf8(fast_exp2(em_j[(size_t)(fwd ? 0 : 511) * N] * LOG2E));
    float C = 0.f;
    const int NS = fwd ? 255 : 256;                        // steps this half-chain
    float em1 = em_j[(size_t)(fwd ? 1 : 510) * N];
    float em2 = em_j[(size_t)(fwd ? 2 : 509) * N];
    SYNC_LDS();

    // pointer-swap double buffering: rb = read buf (s-1 parity), wb = write buf.
    const unsigned char* rb = u_lds[0];
    unsigned char*       wb = u_lds[1];

#define LOAD_UA()                                                              \
    const uint4* ub4 = (const uint4*)rb;                                       \
    uint4 a0 = ub4[2 * lg],     a1 = ub4[2 * lg + 1];                          \
    uint4 b0 = ub4[8 + 2 * lg], b1 = ub4[8 + 2 * lg + 1];                      \
    i8v ua0, ua1;                                                              \
    ua0[0]=a0.x; ua0[1]=a0.y; ua0[2]=a0.z; ua0[3]=a0.w;                        \
    ua0[4]=a1.x; ua0[5]=a1.y; ua0[6]=a1.z; ua0[7]=a1.w;                        \
    ua1[0]=b0.x; ua1[1]=b0.y; ua1[2]=b0.z; ua1[3]=b0.w;                        \
    ua1[4]=b1.x; ua1[5]=b1.y; ua1[6]=b1.z; ua1[7]=b1.w;                        \
    const unsigned int u0b = rb[0];

#define MFMA_BLOCK()                                                                                   \
    f4v z = {0.f, 0.f, 0.f, 0.f};                                                                      \
    f4v d0 = z, d1 = z, d2 = z, d3 = z;                                                                \
    d0 = __builtin_amdgcn_mfma_scale_f32_16x16x128_f8f6f4(ua0, Efr[0][0], d0, 1, 0, 0, SC1, 0, SC1);   \
    d1 = __builtin_amdgcn_mfma_scale_f32_16x16x128_f8f6f4(ua0, Efr[1][0], d1, 1, 0, 0, SC1, 0, SC1);   \
    d2 = __builtin_amdgcn_mfma_scale_f32_16x16x128_f8f6f4(ua0, Efr[2][0], d2, 1, 0, 0, SC1, 0, SC1);   \
    d3 = __builtin_amdgcn_mfma_scale_f32_16x16x128_f8f6f4(ua0, Efr[3][0], d3, 1, 0, 0, SC1, 0, SC1);   \
    d0 = __builtin_amdgcn_mfma_scale_f32_16x16x128_f8f6f4(ua1, Efr[0][1], d0, 1, 0, 0, SC1, 0, SC1);   \
    d1 = __builtin_amdgcn_mfma_scale_f32_16x16x128_f8f6f4(ua1, Efr[1][1], d1, 1, 0, 0, SC1, 0, SC1);   \
    d2 = __builtin_amdgcn_mfma_scale_f32_16x16x128_f8f6f4(ua1, Efr[2][1], d2, 1, 0, 0, SC1, 0, SC1);   \
    d3 = __builtin_amdgcn_mfma_scale_f32_16x16x128_f8f6f4(ua1, Efr[3][1], d3, 1, 0, 0, SC1, 0, SC1);   \
    const float A0 = (lg == 0) ? d0[0] : (lg == 1) ? d1[0] : (lg == 2) ? d2[0] : d3[0];

    #pragma unroll 2
    for (int s = 1; s < NS; ++s) {
        LOAD_UA();

        float em = em1;
        em1 = em2;
        // branchless clamped prefetch (always in-bounds; zeroed when past range)
        {
            const int  idxf = (s + 2 > 255) ? 255 : (s + 2);
            const int  idx  = fwd ? idxf : (509 - s);
            const float emL = em_j[(size_t)idx * N];
            em2 = (s + 2 < 256) ? emL : 0.0f;
        }

        // hoisted scale: k from prev u(0)'s e5m2 exponent; r = 2^-(k+6) exact
        const int   eb   = (int)((u0b >> 2) & 0x1fu);
        const int   k    = (eb ? eb : 1) - 15;
        const float r    = __int_as_float((121 - k) << 23);
        const float gain = fast_exp2(fmaf(em, LOG2E, cm2));
        const float sc   = gain * r;

        MFMA_BLOCK();

        C += (float)(k + 6);
        wb[j] = f2bf8(A0 * sc);              // short tail: mul, cvt, byte write
        { unsigned char* t = wb; wb = (unsigned char*)rb; rb = t; }
        SYNC_LDS();
    }

    // ---- peeled final step: keep unrenormalized value, no trailing barrier ----
    float vfin;
    {
        LOAD_UA();
        (void)u0b;
        const float gain = fast_exp2(fmaf(em1, LOG2E, cm2));
        MFMA_BLOCK();
        vfin = A0 * gain;
    }

    if (fwd) { V[(size_t)b * 256 + j] = vfin; if (j == 0) CF[b] = C; }
    else     { W[(size_t)b * 256 + j] = vfin; if (j == 0) CB[b] = C; }
#undef LOAD_UA
#undef MFMA_BLOCK
}

// Fused tail: per-batch combine (dot + gold score) then last-block mean.
__global__ void crf_tail(const float* __restrict__ emissions,
                         const int*   __restrict__ tags,
                         const float* __restrict__ mask,
                         const float* __restrict__ trans,
                         const float* __restrict__ V,  const float* __restrict__ W,
                         const float* __restrict__ CF, const float* __restrict__ CB,
                         float* __restrict__ ws2, int* __restrict__ counter,
                         float* __restrict__ out) {
    const int T = 512, N = 256;
    const int b = blockIdx.x, j = threadIdx.x;
    __shared__ float red[256];
    __shared__ int ticket;

    red[j] = V[(size_t)b * 256 + j] * W[(size_t)b * 256 + j];
    __syncthreads();
    #pragma unroll
    for (int s = 128; s > 0; s >>= 1) {
        if (j < s) red[j] += red[j + s];
        __syncthreads();
    }
    const float Z = (CF[b] + CB[b] + log2f(red[0])) * LN2;
    __syncthreads();

    float gp = 0.f;
    const int*   tg  = tags + (size_t)b * T;
    const float* mk  = mask + (size_t)b * T;
    const float* emb = emissions + ((size_t)b * T) * N;
    for (int t = 1 + j; t < T; t += 256) {
        int tt = tg[t], tp = tg[t - 1];
        gp += (emb[(size_t)t * N + tt] + trans[(size_t)tp * N + tt]) * mk[t];
    }
    if (j == 0) gp += emb[tg[0]];
    red[j] = gp;
    __syncthreads();
    #pragma unroll
    for (int s = 128; s > 0; s >>= 1) {
        if (j < s) red[j] += red[j + s];
        __syncthreads();
    }
    if (j == 0) {
        ws2[b] = Z - red[0];
        __threadfence();
        ticket = atomicAdd(counter, 1);
    }
    __syncthreads();
    if (ticket == 127 && j < 64) {          // last block: deterministic mean
        __threadfence();
        volatile const float* wv = ws2;
        float s = wv[j] + wv[j + 64];
        #pragma unroll
        for (int d = 32; d > 0; d >>= 1) s += __shfl_down(s, d);
        if (j == 0) out[0] = s * (1.0f / 128.0f);
    }
}

extern "C" void kernel_launch(void* const* d_in, const int* in_sizes, int n_in,
                              void* d_out, int out_size, void* d_ws, size_t ws_size,
                              hipStream_t stream) {
    const float* emissions = (const float*)d_in[0];
    const int*   tags      = (const int*)  d_in[1];
    const float* mask      = (const float*)d_in[2];
    const float* trans     = (const float*)d_in[3];
    float* out = (float*)d_out;

    float* wsf = (float*)d_ws;  // V[32768] W[32768] CF[128] CB[128] ws2[128] counter[1]
    float* V    = wsf;
    float* W    = wsf + 32768;
    float* CF   = wsf + 65536;
    float* CB   = wsf + 65664;
    float* ws2  = wsf + 65792;
    int*   cnt  = (int*)(wsf + 65920);

    crf_main<<<dim3(256), dim3(256), 0, stream>>>(emissions, trans, V, W, CF, CB, cnt);
    crf_tail<<<dim3(128), dim3(256), 0, stream>>>(emissions, tags, mask, trans,
                                                  V, W, CF, CB, ws2, cnt, out);
}

// Round 15
// 136.722 us; speedup vs baseline: 1.2450x; 1.2450x over previous
//
#include <hip/hip_runtime.h>

typedef float f4v __attribute__((ext_vector_type(4)));   // MFMA accumulator
typedef int   i8v __attribute__((ext_vector_type(8)));   // 32 fp8 bytes (8 VGPRs)

#define LOG2E 1.4426950408889634f
#define LN2   0.6931471805599453f
#define SC1   0x7F7F7F7F   // four e8m0 scale factors of 1.0

// Raw barrier: LDS visibility only (lgkmcnt); vmcnt floats -> global prefetch stays async.
#define SYNC_LDS() __asm__ __volatile__("s_waitcnt lgkmcnt(0)\n\ts_barrier" ::: "memory")

__device__ __forceinline__ float fast_exp2(float x) {
#if __has_builtin(__builtin_amdgcn_exp2f)
    return __builtin_amdgcn_exp2f(x);
#else
    return exp2f(x);
#endif
}

// f32 -> bf8 (e5m2) low byte. e5m2 range ~2^-16..2^15.5 absorbs stale-renorm drift.
__device__ __forceinline__ unsigned char f2bf8(float x) {
    return (unsigned char)(__builtin_amdgcn_cvt_pk_bf8_f32(x, x, 0, false) & 0xff);
}

// MIDDLE-MEET (R13-proven main loop, byte-identical): 256 blocks.
// Blocks 0..127: forward chain of batch b: v_t = diag(g_t) E^T v_{t-1}, 255 steps
//   (E-COLUMN frags, colmax norm). Blocks 128..255: backward chain,
//   w_{t-1} = E (g_t (*) w_t), 256 steps (E-ROW frags, rowmax norm; final step
//   applies rowmax only). Z_b = ln(v_255 . w_255) + (C_f + C_b) ln2.
// Engine: 4 waves, K=128 MX MFMA (scales=1.0), bf8 u / fp8 E, one raw barrier,
// stale-u(0) exact-pow2 renorm with C accounting. R15 = R13 + fused tail kernel.
__launch_bounds__(256, 1)
__global__ void crf_main(const float* __restrict__ emissions,
                         const float* __restrict__ trans,
                         float* __restrict__ V,  float* __restrict__ W,
                         float* __restrict__ CF, float* __restrict__ CB,
                         int* __restrict__ counter) {
    const int T = 512, N = 256;
    const bool fwd = blockIdx.x < 128;
    const int b  = fwd ? blockIdx.x : blockIdx.x - 128;
    const int j  = threadIdx.x;
    const int l  = j & 63;          // lane
    const int w  = j >> 6;          // wave
    const int lg = l >> 4;          // 16-lane group (K sub-chunk)
    const int ll = l & 15;          // position in group (N dim)

    if (blockIdx.x == 0 && j == 0) *counter = 0;   // reset tail-kernel ticket

    __shared__ alignas(16) unsigned char u_lds[2][256];  // u as bf8, double-buffered
    __shared__ float cm2_lds[256];

    // ---- per-state log2 normalizer: fwd = colmax(trans[:,j]), bwd = rowmax(trans[j,:]) ----
    if (fwd) {
        const float* tcol = trans + j;
        float m = -1e30f;
        #pragma unroll 8
        for (int i = 0; i < N; ++i) m = fmaxf(m, tcol[i * N]);
        cm2_lds[j] = m * LOG2E;
    } else {
        const float4* trow = (const float4*)(trans + (size_t)j * N);
        float m = -1e30f;
        #pragma unroll 8
        for (int i = 0; i < 64; ++i) {
            float4 t4 = trow[i];
            m = fmaxf(m, fmaxf(fmaxf(t4.x, t4.y), fmaxf(t4.z, t4.w)));
        }
        cm2_lds[j] = m * LOG2E;
    }
    __syncthreads();
    const float cm2 = cm2_lds[j];   // own state's normalizer

    // ---- E fragments (B operand) as fp8 e4m3, identity k-map (byte-slot == k) ----
    // tile c covers output states 64w+16c+ll. fwd: E[k][col] (strided reads);
    // bwd: E[col][k] (contiguous float4 reads).
    i8v Efr[4][2];
    #pragma unroll
    for (int c = 0; c < 4; ++c) {
        const int   col = 64 * w + 16 * c + ll;
        const float cc  = cm2_lds[col];
        #pragma unroll
        for (int q = 0; q < 2; ++q) {
            i8v ev;
            #pragma unroll
            for (int d = 0; d < 8; ++d) {
                const int k0 = 128 * q + 32 * lg + 4 * d;
                float f0, f1, f2, f3;
                if (fwd) {
                    f0 = fast_exp2(trans[(size_t)(k0 + 0) * N + col] * LOG2E - cc);
                    f1 = fast_exp2(trans[(size_t)(k0 + 1) * N + col] * LOG2E - cc);
                    f2 = fast_exp2(trans[(size_t)(k0 + 2) * N + col] * LOG2E - cc);
                    f3 = fast_exp2(trans[(size_t)(k0 + 3) * N + col] * LOG2E - cc);
                } else {
                    float4 t4 = *(const float4*)(trans + (size_t)col * N + k0);
                    f0 = fast_exp2(t4.x * LOG2E - cc);
                    f1 = fast_exp2(t4.y * LOG2E - cc);
                    f2 = fast_exp2(t4.z * LOG2E - cc);
                    f3 = fast_exp2(t4.w * LOG2E - cc);
                }
                int pk = __builtin_amdgcn_cvt_pk_fp8_f32(f0, f1, 0, false);
                pk     = __builtin_amdgcn_cvt_pk_fp8_f32(f2, f3, pk, true);
                ev[d] = pk;
            }
            Efr[c][q] = ev;
        }
    }

    // ---- init: u = bf8(2^(log2e * emit[first])), C = 0; depth-2 em prefetch ----
    const float* em_j = emissions + ((size_t)b * T) * N + j;
    u_lds[0][j] = f2bf8(fast_exp2(em_j[(size_t)(fwd ? 0 : 511) * N] * LOG2E));
    float C = 0.f;
    const int NS = fwd ? 255 : 256;                        // steps this half-chain
    float em1 = em_j[(size_t)(fwd ? 1 : 510) * N];
    float em2 = em_j[(size_t)(fwd ? 2 : 509) * N];
    SYNC_LDS();

    float vfin = 0.f;                                      // final unrenormalized value

    for (int s = 1; s <= NS; ++s) {
        const int pb = (s - 1) & 1;
        // u fragments: chunk q -> 32 bytes at offset 128q + 32lg (16-lane broadcast
        // groups, distinct banks: conflict-free) + u(0) byte broadcast
        const uint4* ub4 = (const uint4*)u_lds[pb];
        uint4 a0 = ub4[2 * lg],     a1 = ub4[2 * lg + 1];      // q = 0
        uint4 b0 = ub4[8 + 2 * lg], b1 = ub4[8 + 2 * lg + 1];  // q = 1
        i8v ua0, ua1;
        ua0[0]=a0.x; ua0[1]=a0.y; ua0[2]=a0.z; ua0[3]=a0.w;
        ua0[4]=a1.x; ua0[5]=a1.y; ua0[6]=a1.z; ua0[7]=a1.w;
        ua1[0]=b0.x; ua1[1]=b0.y; ua1[2]=b0.z; ua1[3]=b0.w;
        ua1[4]=b1.x; ua1[5]=b1.y; ua1[6]=b1.z; ua1[7]=b1.w;
        const unsigned int u0b = u_lds[pb][0];   // exponent reference (bf8 byte)

        float em = em1;
        em1 = em2;
        // bwd consumes em indices 510..256 then 0 at the final step; fwd: 1..255.
        em2 = (s + 2 < 256) ? em_j[(size_t)(fwd ? (s + 2) : (509 - s)) * N] : 0.0f;

        // ---- hoisted scale: k from prev u(0)'s e5m2 exponent; r = 2^-(k+6) exact ----
        const int   eb   = (int)((u0b >> 2) & 0x1fu);
        const int   k    = (eb ? eb : 1) - 15;
        const float r    = __int_as_float((121 - k) << 23);    // 2^-(k+6)
        const float gain = fast_exp2(fmaf(em, LOG2E, cm2));    // emit + normalizer fold-in
        const float sc   = gain * r;

        // ---- MFMA block: 4 tiles x 2 K-chunks, depth-2 accumulate chains ----
        f4v z = {0.f, 0.f, 0.f, 0.f};
        f4v d0 = z, d1 = z, d2 = z, d3 = z;
        d0 = __builtin_amdgcn_mfma_scale_f32_16x16x128_f8f6f4(ua0, Efr[0][0], d0, 1, 0, 0, SC1, 0, SC1);
        d1 = __builtin_amdgcn_mfma_scale_f32_16x16x128_f8f6f4(ua0, Efr[1][0], d1, 1, 0, 0, SC1, 0, SC1);
        d2 = __builtin_amdgcn_mfma_scale_f32_16x16x128_f8f6f4(ua0, Efr[2][0], d2, 1, 0, 0, SC1, 0, SC1);
        d3 = __builtin_amdgcn_mfma_scale_f32_16x16x128_f8f6f4(ua0, Efr[3][0], d3, 1, 0, 0, SC1, 0, SC1);
        d0 = __builtin_amdgcn_mfma_scale_f32_16x16x128_f8f6f4(ua1, Efr[0][1], d0, 1, 0, 0, SC1, 0, SC1);
        d1 = __builtin_amdgcn_mfma_scale_f32_16x16x128_f8f6f4(ua1, Efr[1][1], d1, 1, 0, 0, SC1, 0, SC1);
        d2 = __builtin_amdgcn_mfma_scale_f32_16x16x128_f8f6f4(ua1, Efr[2][1], d2, 1, 0, 0, SC1, 0, SC1);
        d3 = __builtin_amdgcn_mfma_scale_f32_16x16x128_f8f6f4(ua1, Efr[3][1], d3, 1, 0, 0, SC1, 0, SC1);

        // rows replicated; thread j's state sits in tile lg, element 0. Static select.
        const float A0 = (lg == 0) ? d0[0] : (lg == 1) ? d1[0] : (lg == 2) ? d2[0] : d3[0];

        if (s < NS) {
            C += (float)(k + 6);
            u_lds[s & 1][j] = f2bf8(A0 * sc);    // short tail: mul, cvt, byte write
        } else {
            vfin = A0 * gain;                    // final step: keep unrenormalized
        }
        SYNC_LDS();
    }

    if (fwd) { V[(size_t)b * 256 + j] = vfin; if (j == 0) CF[b] = C; }
    else     { W[(size_t)b * 256 + j] = vfin; if (j == 0) CB[b] = C; }
}

// Fused tail: per-batch combine (dot + gold score) then last-block mean.
__global__ void crf_tail(const float* __restrict__ emissions,
                         const int*   __restrict__ tags,
                         const float* __restrict__ mask,
                         const float* __restrict__ trans,
                         const float* __restrict__ V,  const float* __restrict__ W,
                         const float* __restrict__ CF, const float* __restrict__ CB,
                         float* __restrict__ ws2, int* __restrict__ counter,
                         float* __restrict__ out) {
    const int T = 512, N = 256;
    const int b = blockIdx.x, j = threadIdx.x;
    __shared__ float red[256];
    __shared__ int ticket;

    red[j] = V[(size_t)b * 256 + j] * W[(size_t)b * 256 + j];
    __syncthreads();
    #pragma unroll
    for (int s = 128; s > 0; s >>= 1) {
        if (j < s) red[j] += red[j + s];
        __syncthreads();
    }
    const float Z = (CF[b] + CB[b] + log2f(red[0])) * LN2;
    __syncthreads();

    float gp = 0.f;
    const int*   tg  = tags + (size_t)b * T;
    const float* mk  = mask + (size_t)b * T;
    const float* emb = emissions + ((size_t)b * T) * N;
    for (int t = 1 + j; t < T; t += 256) {
        int tt = tg[t], tp = tg[t - 1];
        gp += (emb[(size_t)t * N + tt] + trans[(size_t)tp * N + tt]) * mk[t];
    }
    if (j == 0) gp += emb[tg[0]];
    red[j] = gp;
    __syncthreads();
    #pragma unroll
    for (int s = 128; s > 0; s >>= 1) {
        if (j < s) red[j] += red[j + s];
        __syncthreads();
    }
    if (j == 0) {
        ws2[b] = Z - red[0];
        __threadfence();
        ticket = atomicAdd(counter, 1);
    }
    __syncthreads();
    if (ticket == 127 && j < 64) {          // last block: deterministic mean
        __threadfence();
        volatile const float* wv = ws2;
        float s = wv[j] + wv[j + 64];
        #pragma unroll
        for (int d = 32; d > 0; d >>= 1) s += __shfl_down(s, d);
        if (j == 0) out[0] = s * (1.0f / 128.0f);
    }
}

extern "C" void kernel_launch(void* const* d_in, const int* in_sizes, int n_in,
                              void* d_out, int out_size, void* d_ws, size_t ws_size,
                              hipStream_t stream) {
    const float* emissions = (const float*)d_in[0];
    const int*   tags      = (const int*)  d_in[1];
    const float* mask      = (const float*)d_in[2];
    const float* trans     = (const float*)d_in[3];
    float* out = (float*)d_out;

    float* wsf = (float*)d_ws;  // V[32768] W[32768] CF[128] CB[128] ws2[128] counter[1]
    float* V    = wsf;
    float* W    = wsf + 32768;
    float* CF   = wsf + 65536;
    float* CB   = wsf + 65664;
    float* ws2  = wsf + 65792;
    int*   cnt  = (int*)(wsf + 65920);

    crf_main<<<dim3(256), dim3(256), 0, stream>>>(emissions, trans, V, W, CF, CB, cnt);
    crf_tail<<<dim3(128), dim3(256), 0, stream>>>(emissions, tags, mask, trans,
                                                  V, W, CF, CB, ws2, cnt, out);
}

// Round 16
// 128.273 us; speedup vs baseline: 1.3271x; 1.0659x over previous
//
#include <hip/hip_runtime.h>

typedef float f4v __attribute__((ext_vector_type(4)));   // MFMA accumulator
typedef int   i8v __attribute__((ext_vector_type(8)));   // 32 fp8 bytes (8 VGPRs)

#define LOG2E 1.4426950408889634f
#define LN2   0.6931471805599453f
#define SC1   0x7F7F7F7F   // four e8m0 scale factors of 1.0

// Raw barrier: LDS visibility only (lgkmcnt); vmcnt floats -> global prefetch stays async.
#define SYNC_LDS() __asm__ __volatile__("s_waitcnt lgkmcnt(0)\n\ts_barrier" ::: "memory")

__device__ __forceinline__ float fast_exp2(float x) {
#if __has_builtin(__builtin_amdgcn_exp2f)
    return __builtin_amdgcn_exp2f(x);
#else
    return exp2f(x);
#endif
}

// f32 -> bf8 (e5m2) low byte. e5m2 range ~2^-16..2^15.5 absorbs stale-renorm drift.
__device__ __forceinline__ unsigned char f2bf8(float x) {
    return (unsigned char)(__builtin_amdgcn_cvt_pk_bf8_f32(x, x, 0, false) & 0xff);
}

// MIDDLE-MEET (R13/R15-proven): 256 blocks. Blocks 0..127: forward chain of batch b:
//   v_t = diag(g_t) E^T v_{t-1}, 255 steps (E-COLUMN frags, colmax norm).
// Blocks 128..255: backward chain, w_{t-1} = E (g_t (*) w_t), 256 steps
//   (E-ROW frags, rowmax norm; final step applies rowmax only).
// Z_b = ln(v_255 . w_255) + (C_f + C_b) ln2.
// Engine: 4 waves, K=128 MX MFMA (scales=1.0), bf8 u / fp8 E, one raw barrier/step,
// stale-u(0) exact-pow2 renorm with C accounting.
// R16: 2x-unrolled loop with STATIC LDS buffer indices (offset-folded ds ops),
// peeled final step (static per-direction parity), pointer-bump em prefetch.
__launch_bounds__(256, 1)
__global__ void crf_main(const float* __restrict__ emissions,
                         const float* __restrict__ trans,
                         float* __restrict__ V,  float* __restrict__ W,
                         float* __restrict__ CF, float* __restrict__ CB,
                         int* __restrict__ counter) {
    const int T = 512, N = 256;
    const bool fwd = blockIdx.x < 128;
    const int b  = fwd ? blockIdx.x : blockIdx.x - 128;
    const int j  = threadIdx.x;
    const int l  = j & 63;          // lane
    const int w  = j >> 6;          // wave
    const int lg = l >> 4;          // 16-lane group (K sub-chunk)
    const int ll = l & 15;          // position in group (N dim)

    if (blockIdx.x == 0 && j == 0) *counter = 0;   // reset tail-kernel ticket

    __shared__ alignas(16) unsigned char u_lds[2][256];  // u as bf8, double-buffered
    __shared__ float cm2_lds[256];

    // ---- per-state log2 normalizer: fwd = colmax(trans[:,j]), bwd = rowmax(trans[j,:]) ----
    if (fwd) {
        const float* tcol = trans + j;
        float m = -1e30f;
        #pragma unroll 8
        for (int i = 0; i < N; ++i) m = fmaxf(m, tcol[i * N]);
        cm2_lds[j] = m * LOG2E;
    } else {
        const float4* trow = (const float4*)(trans + (size_t)j * N);
        float m = -1e30f;
        #pragma unroll 8
        for (int i = 0; i < 64; ++i) {
            float4 t4 = trow[i];
            m = fmaxf(m, fmaxf(fmaxf(t4.x, t4.y), fmaxf(t4.z, t4.w)));
        }
        cm2_lds[j] = m * LOG2E;
    }
    __syncthreads();
    const float cm2 = cm2_lds[j];   // own state's normalizer

    // ---- E fragments (B operand) as fp8 e4m3, identity k-map (byte-slot == k) ----
    i8v Efr[4][2];
    #pragma unroll
    for (int c = 0; c < 4; ++c) {
        const int   col = 64 * w + 16 * c + ll;
        const float cc  = cm2_lds[col];
        #pragma unroll
        for (int q = 0; q < 2; ++q) {
            i8v ev;
            #pragma unroll
            for (int d = 0; d < 8; ++d) {
                const int k0 = 128 * q + 32 * lg + 4 * d;
                float f0, f1, f2, f3;
                if (fwd) {
                    f0 = fast_exp2(trans[(size_t)(k0 + 0) * N + col] * LOG2E - cc);
                    f1 = fast_exp2(trans[(size_t)(k0 + 1) * N + col] * LOG2E - cc);
                    f2 = fast_exp2(trans[(size_t)(k0 + 2) * N + col] * LOG2E - cc);
                    f3 = fast_exp2(trans[(size_t)(k0 + 3) * N + col] * LOG2E - cc);
                } else {
                    float4 t4 = *(const float4*)(trans + (size_t)col * N + k0);
                    f0 = fast_exp2(t4.x * LOG2E - cc);
                    f1 = fast_exp2(t4.y * LOG2E - cc);
                    f2 = fast_exp2(t4.z * LOG2E - cc);
                    f3 = fast_exp2(t4.w * LOG2E - cc);
                }
                int pk = __builtin_amdgcn_cvt_pk_fp8_f32(f0, f1, 0, false);
                pk     = __builtin_amdgcn_cvt_pk_fp8_f32(f2, f3, pk, true);
                ev[d] = pk;
            }
            Efr[c][q] = ev;
        }
    }

    // ---- init: u = bf8(2^(log2e * emit[first])), C = 0; depth-2 em prefetch ----
    const float* em_j = emissions + ((size_t)b * T) * N + j;
    u_lds[0][j] = f2bf8(fast_exp2(em_j[(size_t)(fwd ? 0 : 511) * N] * LOG2E));
    float C = 0.f;
    const int NS = fwd ? 255 : 256;                        // steps this half-chain
    float em1 = em_j[(size_t)(fwd ? 1 : 510) * N];
    float em2 = em_j[(size_t)(fwd ? 2 : 509) * N];
    const float* emp = em_j + (size_t)(fwd ? 3 : 508) * N; // next prefetch address
    const ptrdiff_t dstep = fwd ? N : -N;                  // bump per step
    SYNC_LDS();

    float vfin = 0.f;                                      // final unrenormalized value

    // One step, compile-time LDS buffer indices RB (read) / WBx (write).
#define BODY(S, RB, WB)  do {                                                                          \
    const uint4* ub4 = (const uint4*)u_lds[RB];                                                        \
    uint4 a0 = ub4[2 * lg],     a1 = ub4[2 * lg + 1];                                                  \
    uint4 b0 = ub4[8 + 2 * lg], b1 = ub4[8 + 2 * lg + 1];                                              \
    i8v ua0, ua1;                                                                                      \
    ua0[0]=a0.x; ua0[1]=a0.y; ua0[2]=a0.z; ua0[3]=a0.w;                                                \
    ua0[4]=a1.x; ua0[5]=a1.y; ua0[6]=a1.z; ua0[7]=a1.w;                                                \
    ua1[0]=b0.x; ua1[1]=b0.y; ua1[2]=b0.z; ua1[3]=b0.w;                                                \
    ua1[4]=b1.x; ua1[5]=b1.y; ua1[6]=b1.z; ua1[7]=b1.w;                                                \
    const unsigned int u0b = u_lds[RB][0];                                                             \
    const float em = em1; em1 = em2;                                                                   \
    { const float emL = *emp; emp += dstep; em2 = ((S) + 2 < 256) ? emL : 0.0f; }                      \
    const int   eb   = (int)((u0b >> 2) & 0x1fu);                                                      \
    const int   k    = (eb ? eb : 1) - 15;                                                             \
    const float r    = __int_as_float((121 - k) << 23);                                                \
    const float gain = fast_exp2(fmaf(em, LOG2E, cm2));                                                \
    const float sc   = gain * r;                                                                       \
    f4v z = {0.f, 0.f, 0.f, 0.f};                                                                      \
    f4v d0 = z, d1 = z, d2 = z, d3 = z;                                                                \
    d0 = __builtin_amdgcn_mfma_scale_f32_16x16x128_f8f6f4(ua0, Efr[0][0], d0, 1, 0, 0, SC1, 0, SC1);   \
    d1 = __builtin_amdgcn_mfma_scale_f32_16x16x128_f8f6f4(ua0, Efr[1][0], d1, 1, 0, 0, SC1, 0, SC1);   \
    d2 = __builtin_amdgcn_mfma_scale_f32_16x16x128_f8f6f4(ua0, Efr[2][0], d2, 1, 0, 0, SC1, 0, SC1);   \
    d3 = __builtin_amdgcn_mfma_scale_f32_16x16x128_f8f6f4(ua0, Efr[3][0], d3, 1, 0, 0, SC1, 0, SC1);   \
    d0 = __builtin_amdgcn_mfma_scale_f32_16x16x128_f8f6f4(ua1, Efr[0][1], d0, 1, 0, 0, SC1, 0, SC1);   \
    d1 = __builtin_amdgcn_mfma_scale_f32_16x16x128_f8f6f4(ua1, Efr[1][1], d1, 1, 0, 0, SC1, 0, SC1);   \
    d2 = __builtin_amdgcn_mfma_scale_f32_16x16x128_f8f6f4(ua1, Efr[2][1], d2, 1, 0, 0, SC1, 0, SC1);   \
    d3 = __builtin_amdgcn_mfma_scale_f32_16x16x128_f8f6f4(ua1, Efr[3][1], d3, 1, 0, 0, SC1, 0, SC1);   \
    const float A0 = (lg == 0) ? d0[0] : (lg == 1) ? d1[0] : (lg == 2) ? d2[0] : d3[0];                \
    C += (float)(k + 6);                                                                               \
    u_lds[WB][j] = f2bf8(A0 * sc);                                                                     \
    SYNC_LDS();                                                                                        \
} while (0)

    // Final step (step NS): reads buffer FB, applies gain only, no write/barrier.
#define FINAL(FB)  do {                                                                                \
    const uint4* ub4 = (const uint4*)u_lds[FB];                                                        \
    uint4 a0 = ub4[2 * lg],     a1 = ub4[2 * lg + 1];                                                  \
    uint4 b0 = ub4[8 + 2 * lg], b1 = ub4[8 + 2 * lg + 1];                                              \
    i8v ua0, ua1;                                                                                      \
    ua0[0]=a0.x; ua0[1]=a0.y; ua0[2]=a0.z; ua0[3]=a0.w;                                                \
    ua0[4]=a1.x; ua0[5]=a1.y; ua0[6]=a1.z; ua0[7]=a1.w;                                                \
    ua1[0]=b0.x; ua1[1]=b0.y; ua1[2]=b0.z; ua1[3]=b0.w;                                                \
    ua1[4]=b1.x; ua1[5]=b1.y; ua1[6]=b1.z; ua1[7]=b1.w;                                                \
    const float gain = fast_exp2(fmaf(em1, LOG2E, cm2));                                               \
    f4v z = {0.f, 0.f, 0.f, 0.f};                                                                      \
    f4v d0 = z, d1 = z, d2 = z, d3 = z;                                                                \
    d0 = __builtin_amdgcn_mfma_scale_f32_16x16x128_f8f6f4(ua0, Efr[0][0], d0, 1, 0, 0, SC1, 0, SC1);   \
    d1 = __builtin_amdgcn_mfma_scale_f32_16x16x128_f8f6f4(ua0, Efr[1][0], d1, 1, 0, 0, SC1, 0, SC1);   \
    d2 = __builtin_amdgcn_mfma_scale_f32_16x16x128_f8f6f4(ua0, Efr[2][0], d2, 1, 0, 0, SC1, 0, SC1);   \
    d3 = __builtin_amdgcn_mfma_scale_f32_16x16x128_f8f6f4(ua0, Efr[3][0], d3, 1, 0, 0, SC1, 0, SC1);   \
    d0 = __builtin_amdgcn_mfma_scale_f32_16x16x128_f8f6f4(ua1, Efr[0][1], d0, 1, 0, 0, SC1, 0, SC1);   \
    d1 = __builtin_amdgcn_mfma_scale_f32_16x16x128_f8f6f4(ua1, Efr[1][1], d1, 1, 0, 0, SC1, 0, SC1);   \
    d2 = __builtin_amdgcn_mfma_scale_f32_16x16x128_f8f6f4(ua1, Efr[2][1], d2, 1, 0, 0, SC1, 0, SC1);   \
    d3 = __builtin_amdgcn_mfma_scale_f32_16x16x128_f8f6f4(ua1, Efr[3][1], d3, 1, 0, 0, SC1, 0, SC1);   \
    const float A0 = (lg == 0) ? d0[0] : (lg == 1) ? d1[0] : (lg == 2) ? d2[0] : d3[0];                \
    vfin = A0 * gain;                                                                                  \
} while (0)

    int s = 1;
    for (; s + 1 < NS; s += 2) {     // pairs with static parities (s odd -> RB=0)
        BODY(s,     0, 1);
        BODY(s + 1, 1, 0);
    }
    if (s < NS) BODY(s, 0, 1);       // leftover looped step (bwd only; s odd -> RB=0)
    if (fwd) FINAL(0); else FINAL(1);  // step NS reads (NS-1)&1: fwd 0, bwd 1
#undef BODY
#undef FINAL

    if (fwd) { V[(size_t)b * 256 + j] = vfin; if (j == 0) CF[b] = C; }
    else     { W[(size_t)b * 256 + j] = vfin; if (j == 0) CB[b] = C; }
}

// Fused tail: per-batch combine (dot + gold score) then last-block mean.
__global__ void crf_tail(const float* __restrict__ emissions,
                         const int*   __restrict__ tags,
                         const float* __restrict__ mask,
                         const float* __restrict__ trans,
                         const float* __restrict__ V,  const float* __restrict__ W,
                         const float* __restrict__ CF, const float* __restrict__ CB,
                         float* __restrict__ ws2, int* __restrict__ counter,
                         float* __restrict__ out) {
    const int T = 512, N = 256;
    const int b = blockIdx.x, j = threadIdx.x;
    __shared__ float red[256];
    __shared__ int ticket;

    red[j] = V[(size_t)b * 256 + j] * W[(size_t)b * 256 + j];
    __syncthreads();
    #pragma unroll
    for (int s = 128; s > 0; s >>= 1) {
        if (j < s) red[j] += red[j + s];
        __syncthreads();
    }
    const float Z = (CF[b] + CB[b] + log2f(red[0])) * LN2;
    __syncthreads();

    float gp = 0.f;
    const int*   tg  = tags + (size_t)b * T;
    const float* mk  = mask + (size_t)b * T;
    const float* emb = emissions + ((size_t)b * T) * N;
    for (int t = 1 + j; t < T; t += 256) {
        int tt = tg[t], tp = tg[t - 1];
        gp += (emb[(size_t)t * N + tt] + trans[(size_t)tp * N + tt]) * mk[t];
    }
    if (j == 0) gp += emb[tg[0]];
    red[j] = gp;
    __syncthreads();
    #pragma unroll
    for (int s = 128; s > 0; s >>= 1) {
        if (j < s) red[j] += red[j + s];
        __syncthreads();
    }
    if (j == 0) {
        ws2[b] = Z - red[0];
        __threadfence();
        ticket = atomicAdd(counter, 1);
    }
    __syncthreads();
    if (ticket == 127 && j < 64) {          // last block: deterministic mean
        __threadfence();
        volatile const float* wv = ws2;
        float s = wv[j] + wv[j + 64];
        #pragma unroll
        for (int d = 32; d > 0; d >>= 1) s += __shfl_down(s, d);
        if (j == 0) out[0] = s * (1.0f / 128.0f);
    }
}

extern "C" void kernel_launch(void* const* d_in, const int* in_sizes, int n_in,
                              void* d_out, int out_size, void* d_ws, size_t ws_size,
                              hipStream_t stream) {
    const float* emissions = (const float*)d_in[0];
    const int*   tags      = (const int*)  d_in[1];
    const float* mask      = (const float*)d_in[2];
    const float* trans     = (const float*)d_in[3];
    float* out = (float*)d_out;

    float* wsf = (float*)d_ws;  // V[32768] W[32768] CF[128] CB[128] ws2[128] counter[1]
    float* V    = wsf;
    float* W    = wsf + 32768;
    float* CF   = wsf + 65536;
    float* CB   = wsf + 65664;
    float* ws2  = wsf + 65792;
    int*   cnt  = (int*)(wsf + 65920);

    crf_main<<<dim3(256), dim3(256), 0, stream>>>(emissions, trans, V, W, CF, CB, cnt);
    crf_tail<<<dim3(128), dim3(256), 0, stream>>>(emissions, tags, mask, trans,
                                                  V, W, CF, CB, ws2, cnt, out);
}